// Round 11
// baseline (389.305 us; speedup 1.0000x reference)
//
#include <hip/hip_runtime.h>
#include <hip/hip_bf16.h>

// GAT: N=50000 nodes, E=500000 edges, IN=256, HID=64, H=4 heads (H*HID=256)
#define NN 50000
#define NE 500000
#define C_HH 256  // H*HID

typedef __attribute__((ext_vector_type(8))) short s16x8;
typedef __attribute__((ext_vector_type(4))) float f32x4;
typedef __attribute__((ext_vector_type(4))) unsigned short u16x4;
typedef unsigned short ushort_t;

__device__ __forceinline__ float lrelu(float x) { return x > 0.f ? x : 0.2f * x; }

__device__ __forceinline__ ushort_t f2bf(float f) {
  unsigned u = __float_as_uint(f);
  u = (u + 0x7FFFu + ((u >> 16) & 1u)) >> 16;
  return (ushort_t)u;
}
__device__ __forceinline__ float bf2f(ushort_t u) {
  return __uint_as_float(((unsigned)u) << 16);
}
__device__ __forceinline__ float sel_head(float4 v, int head) {
  const float x0 = (head & 1) ? v.y : v.x;
  const float x1 = (head & 1) ? v.w : v.z;
  return (head & 2) ? x1 : x0;
}

// ---------------- prep: fold embed into W1; fold p1/p2 into a vector ----------------
__global__ __launch_bounds__(256) void prep_kernel(const float* __restrict__ eW,
                                                   const float* __restrict__ W1,
                                                   const float* __restrict__ eb,
                                                   const float* __restrict__ W2,
                                                   const float* __restrict__ p1W,
                                                   const float* __restrict__ p1b,
                                                   const float* __restrict__ p2W,
                                                   const float* __restrict__ p2b,
                                                   ushort_t* __restrict__ WcT,
                                                   ushort_t* __restrict__ w2T,
                                                   float* __restrict__ bc,
                                                   float* __restrict__ qv,
                                                   float* __restrict__ cv) {
  int idx = blockIdx.x * 256 + threadIdx.x;
  if (idx < 65536) {                       // WcT[n][k] = bf16(sum_j eW[k][j]*W1[j][n])
    const int n = idx >> 8, k = idx & 255;
    float s = 0.f;
#pragma unroll 8
    for (int j = 0; j < 64; ++j) s = fmaf(eW[k * 64 + j], W1[j * 256 + n], s);
    WcT[idx] = f2bf(s);
  } else if (idx < 131072) {               // w2T[n][k] = bf16(W2[k][n])
    idx -= 65536;
    const int n = idx >> 8, k = idx & 255;
    w2T[idx] = f2bf(W2[k * 256 + n]);
  } else if (idx < 131328) {               // bc
    const int n = idx - 131072;
    float s = 0.f;
#pragma unroll 8
    for (int j = 0; j < 64; ++j) s = fmaf(eb[j], W1[j * 256 + n], s);
    bc[n] = s;
  } else if (idx < 131584) {               // qv
    const int k = idx - 131328;
    float s = 0.f;
#pragma unroll 8
    for (int j = 0; j < 64; ++j) s = fmaf(p1W[k * 64 + j], p2W[j], s);
    qv[k] = s;
  } else if (idx == 131584) {              // cv
    float s = p2b[0];
    for (int j = 0; j < 64; ++j) s = fmaf(p1b[j], p2W[j], s);
    cv[0] = s;
  }
}

// ---------------- MFMA GEMM [M,256]@[256,256] + fused el/er, deep-MLP form ----------------
// Block = 256 thr = 4 waves, 32 rows/block; wave w owns cols [64w,64w+64) = head w.
// All A + B fragments staged in registers up-front (deep MLP), then 64 MFMAs.
// A_F32: A is fp32, staged as f32 (128 VGPR) and converted in-register (no xb pass).
// C/D layout: col=lane&15, row=(lane>>4)*4+reg (HW-verified r4).
template <bool A_F32, bool BIAS>
__global__ __launch_bounds__(256, 2) void gemm_fused(const void* __restrict__ Ain,
                                                     const ushort_t* __restrict__ WT,
                                                     const float* __restrict__ bc,
                                                     const float* __restrict__ al,
                                                     const float* __restrict__ ar,
                                                     float* __restrict__ el,
                                                     float* __restrict__ er,
                                                     ushort_t* __restrict__ Cout, int M) {
  const int wid = threadIdx.x >> 6;   // head / col-group
  const int lane = threadIdx.x & 63;
  const int row0 = blockIdx.x * 32;
  const int rA = lane & 15;
  const int kg = lane >> 4;
  const int c0 = wid * 64;

  const s16x8 zf = {0, 0, 0, 0, 0, 0, 0, 0};
  const bool v0 = (row0 + rA) < M;
  const bool v1 = (row0 + 16 + rA) < M;
  const ushort_t* Wbase = WT + (size_t)(c0 + rA) * 256;

  s16x8 a0[8], a1[8];
  if (A_F32) {
    const float* Af = (const float*)Ain;
    const float* Ar0 = Af + (size_t)(row0 + rA) * 256;
    const float* Ar1 = Af + (size_t)(row0 + 16 + rA) * 256;
    const f32x4 zf4 = {0.f, 0.f, 0.f, 0.f};
    f32x4 af0[8][2], af1[8][2];
#pragma unroll
    for (int ks = 0; ks < 8; ++ks) {
      const int k0 = ks * 32 + kg * 8;
      af0[ks][0] = v0 ? *reinterpret_cast<const f32x4*>(Ar0 + k0) : zf4;
      af0[ks][1] = v0 ? *reinterpret_cast<const f32x4*>(Ar0 + k0 + 4) : zf4;
      af1[ks][0] = v1 ? *reinterpret_cast<const f32x4*>(Ar1 + k0) : zf4;
      af1[ks][1] = v1 ? *reinterpret_cast<const f32x4*>(Ar1 + k0 + 4) : zf4;
    }
#pragma unroll
    for (int ks = 0; ks < 8; ++ks) {
#pragma unroll
      for (int h = 0; h < 2; ++h) {
#pragma unroll
        for (int j = 0; j < 4; ++j) {
          a0[ks][h * 4 + j] = (short)f2bf(af0[ks][h][j]);
          a1[ks][h * 4 + j] = (short)f2bf(af1[ks][h][j]);
        }
      }
    }
  } else {
    const ushort_t* Ab = (const ushort_t*)Ain;
    const ushort_t* Ar0 = Ab + (size_t)(row0 + rA) * 256;
    const ushort_t* Ar1 = Ab + (size_t)(row0 + 16 + rA) * 256;
#pragma unroll
    for (int ks = 0; ks < 8; ++ks) {
      const int k0 = ks * 32 + kg * 8;
      a0[ks] = v0 ? *reinterpret_cast<const s16x8*>(Ar0 + k0) : zf;
      a1[ks] = v1 ? *reinterpret_cast<const s16x8*>(Ar1 + k0) : zf;
    }
  }

  s16x8 b[8][4];
#pragma unroll
  for (int ks = 0; ks < 8; ++ks) {
    const int k0 = ks * 32 + kg * 8;
#pragma unroll
    for (int nt = 0; nt < 4; ++nt)
      b[ks][nt] = *reinterpret_cast<const s16x8*>(Wbase + nt * 16 * 256 + k0);
  }

  f32x4 acc[2][4] = {};
#pragma unroll
  for (int ks = 0; ks < 8; ++ks) {
#pragma unroll
    for (int nt = 0; nt < 4; ++nt) {
      acc[0][nt] = __builtin_amdgcn_mfma_f32_16x16x32_bf16(a0[ks], b[ks][nt], acc[0][nt], 0, 0, 0);
      acc[1][nt] = __builtin_amdgcn_mfma_f32_16x16x32_bf16(a1[ks], b[ks][nt], acc[1][nt], 0, 0, 0);
    }
  }

  if (BIAS) {
#pragma unroll
    for (int nt = 0; nt < 4; ++nt) {
      const float bv = bc[c0 + nt * 16 + rA];
#pragma unroll
      for (int mt = 0; mt < 2; ++mt)
#pragma unroll
        for (int i = 0; i < 4; ++i) acc[mt][nt][i] += bv;
    }
  }

  // store bf16 C
#pragma unroll
  for (int nt = 0; nt < 4; ++nt) {
    const int col = c0 + nt * 16 + rA;
#pragma unroll
    for (int mt = 0; mt < 2; ++mt) {
#pragma unroll
      for (int i = 0; i < 4; ++i) {
        const int row = row0 + mt * 16 + kg * 4 + i;
        if (row < M) Cout[(size_t)row * 256 + col] = f2bf(acc[mt][nt][i]);
      }
    }
  }

  // fused el/er for head `wid`
  float alv[4], arv[4];
#pragma unroll
  for (int nt = 0; nt < 4; ++nt) {
    alv[nt] = al[c0 + nt * 16 + rA];
    arv[nt] = ar[c0 + nt * 16 + rA];
  }
#pragma unroll
  for (int mt = 0; mt < 2; ++mt) {
#pragma unroll
    for (int i = 0; i < 4; ++i) {
      float e = 0.f, r = 0.f;
#pragma unroll
      for (int nt = 0; nt < 4; ++nt) {
        e = fmaf(acc[mt][nt][i], alv[nt], e);
        r = fmaf(acc[mt][nt][i], arv[nt], r);
      }
#pragma unroll
      for (int m = 1; m < 16; m <<= 1) {
        e += __shfl_xor(e, m);
        r += __shfl_xor(r, m);
      }
      const int row = row0 + mt * 16 + kg * 4 + i;
      if (rA == 0 && row < M) {
        el[row * 4 + wid] = e;
        er[row * 4 + wid] = r;
      }
    }
  }
}

// ---------------- CSR build: histogram -> scan -> scatter ----------------
__global__ __launch_bounds__(256) void hist_kernel(const int* __restrict__ dst,
                                                   int* __restrict__ rowptr) {
  const int e = blockIdx.x * 256 + threadIdx.x;
  if (e < NE) atomicAdd(&rowptr[dst[e]], 1);
}

__global__ __launch_bounds__(256) void scan1_kernel(int* __restrict__ rowptr,
                                                    int* __restrict__ partial) {
  __shared__ int sh[256];
  const int t = threadIdx.x;
  const int i = blockIdx.x * 256 + t;
  const int v = (i < NN) ? rowptr[i] : 0;
  sh[t] = v;
  __syncthreads();
#pragma unroll
  for (int off = 1; off < 256; off <<= 1) {
    int x = (t >= off) ? sh[t - off] : 0;
    __syncthreads();
    sh[t] += x;
    __syncthreads();
  }
  if (i < NN) rowptr[i] = sh[t] - v;
  if (t == 255) partial[blockIdx.x] = sh[255];
}

__global__ __launch_bounds__(256) void scan2_kernel(int* __restrict__ partial, int npb) {
  __shared__ int sh[256];
  const int t = threadIdx.x;
  const int v = (t < npb) ? partial[t] : 0;
  sh[t] = v;
  __syncthreads();
#pragma unroll
  for (int off = 1; off < 256; off <<= 1) {
    int x = (t >= off) ? sh[t - off] : 0;
    __syncthreads();
    sh[t] += x;
    __syncthreads();
  }
  if (t < npb) partial[t] = sh[t] - v;
}

__global__ __launch_bounds__(256) void scan3_kernel(int* __restrict__ rowptr,
                                                    const int* __restrict__ partial,
                                                    int* __restrict__ cursor) {
  const int i = blockIdx.x * 256 + threadIdx.x;
  if (i < NN) {
    const int r = rowptr[i] + partial[i >> 8];
    rowptr[i] = r;
    cursor[i] = r;
  } else if (i == NN) {
    rowptr[NN] = NE;
  }
}

__global__ __launch_bounds__(256) void scatter_kernel(const int* __restrict__ src,
                                                      const int* __restrict__ dst,
                                                      int* __restrict__ cursor,
                                                      int* __restrict__ sorted_src) {
  const int e = blockIdx.x * 256 + threadIdx.x;
  if (e >= NE) return;
  const int pos = atomicAdd(&cursor[dst[e]], 1);
  sorted_src[pos] = src[e];
}

// ---------------- fused per-dst softmax-aggregation + bias + relu (bf16 feat) ----------------
// one 64-lane wave per dst node; lane owns cols 4l..4l+3 (all in head l>>4).
// 8-edge software pipeline (16 outstanding loads), 4-chunk + scalar tail.
// HEAD=true: don't store hout; fuse out[n] = sigmoid(relu_row · qv + cv) instead.
#define EDGE_BODY(SN, AV, FV)                                    \
  {                                                              \
    const float w_ = __expf(lrelu(sel_head(AV, head) + erh));    \
    a0 = fmaf(w_, bf2f(FV[0]), a0);                              \
    a1 = fmaf(w_, bf2f(FV[1]), a1);                              \
    a2 = fmaf(w_, bf2f(FV[2]), a2);                              \
    a3 = fmaf(w_, bf2f(FV[3]), a3);                              \
    s += w_;                                                     \
  }

template <bool HEAD>
__global__ __launch_bounds__(256) void aggr_fused_kernel(const int* __restrict__ rowptr,
                                                         const int* __restrict__ sorted_src,
                                                         const float* __restrict__ el,
                                                         const float* __restrict__ er,
                                                         const ushort_t* __restrict__ featb,
                                                         const float* __restrict__ bias,
                                                         ushort_t* __restrict__ out,
                                                         const float* __restrict__ qv,
                                                         const float* __restrict__ cv,
                                                         float* __restrict__ outf) {
  const int node = blockIdx.x * 4 + (threadIdx.x >> 6);
  const int lane = threadIdx.x & 63;
  const int head = lane >> 4;
  const int start = rowptr[node];
  const int end = rowptr[node + 1];
  const float erh = sel_head(*reinterpret_cast<const float4*>(er + node * 4), head);
  const size_t lofs = (size_t)lane * 4;

  float a0 = 0.f, a1 = 0.f, a2 = 0.f, a3 = 0.f, s = 0.f;
  int e = start;
  for (; e + 8 <= end; e += 8) {
    const int sn0 = sorted_src[e + 0];
    const int sn1 = sorted_src[e + 1];
    const int sn2 = sorted_src[e + 2];
    const int sn3 = sorted_src[e + 3];
    const int sn4 = sorted_src[e + 4];
    const int sn5 = sorted_src[e + 5];
    const int sn6 = sorted_src[e + 6];
    const int sn7 = sorted_src[e + 7];
    const float4 A0 = *reinterpret_cast<const float4*>(el + sn0 * 4);
    const float4 A1 = *reinterpret_cast<const float4*>(el + sn1 * 4);
    const float4 A2 = *reinterpret_cast<const float4*>(el + sn2 * 4);
    const float4 A3 = *reinterpret_cast<const float4*>(el + sn3 * 4);
    const float4 A4 = *reinterpret_cast<const float4*>(el + sn4 * 4);
    const float4 A5 = *reinterpret_cast<const float4*>(el + sn5 * 4);
    const float4 A6 = *reinterpret_cast<const float4*>(el + sn6 * 4);
    const float4 A7 = *reinterpret_cast<const float4*>(el + sn7 * 4);
    const u16x4 F0 = *reinterpret_cast<const u16x4*>(featb + (size_t)sn0 * C_HH + lofs);
    const u16x4 F1 = *reinterpret_cast<const u16x4*>(featb + (size_t)sn1 * C_HH + lofs);
    const u16x4 F2 = *reinterpret_cast<const u16x4*>(featb + (size_t)sn2 * C_HH + lofs);
    const u16x4 F3 = *reinterpret_cast<const u16x4*>(featb + (size_t)sn3 * C_HH + lofs);
    const u16x4 F4 = *reinterpret_cast<const u16x4*>(featb + (size_t)sn4 * C_HH + lofs);
    const u16x4 F5 = *reinterpret_cast<const u16x4*>(featb + (size_t)sn5 * C_HH + lofs);
    const u16x4 F6 = *reinterpret_cast<const u16x4*>(featb + (size_t)sn6 * C_HH + lofs);
    const u16x4 F7 = *reinterpret_cast<const u16x4*>(featb + (size_t)sn7 * C_HH + lofs);
    EDGE_BODY(sn0, A0, F0) EDGE_BODY(sn1, A1, F1)
    EDGE_BODY(sn2, A2, F2) EDGE_BODY(sn3, A3, F3)
    EDGE_BODY(sn4, A4, F4) EDGE_BODY(sn5, A5, F5)
    EDGE_BODY(sn6, A6, F6) EDGE_BODY(sn7, A7, F7)
  }
  if (e + 4 <= end) {
    const int sn0 = sorted_src[e + 0];
    const int sn1 = sorted_src[e + 1];
    const int sn2 = sorted_src[e + 2];
    const int sn3 = sorted_src[e + 3];
    const float4 A0 = *reinterpret_cast<const float4*>(el + sn0 * 4);
    const float4 A1 = *reinterpret_cast<const float4*>(el + sn1 * 4);
    const float4 A2 = *reinterpret_cast<const float4*>(el + sn2 * 4);
    const float4 A3 = *reinterpret_cast<const float4*>(el + sn3 * 4);
    const u16x4 F0 = *reinterpret_cast<const u16x4*>(featb + (size_t)sn0 * C_HH + lofs);
    const u16x4 F1 = *reinterpret_cast<const u16x4*>(featb + (size_t)sn1 * C_HH + lofs);
    const u16x4 F2 = *reinterpret_cast<const u16x4*>(featb + (size_t)sn2 * C_HH + lofs);
    const u16x4 F3 = *reinterpret_cast<const u16x4*>(featb + (size_t)sn3 * C_HH + lofs);
    EDGE_BODY(sn0, A0, F0) EDGE_BODY(sn1, A1, F1)
    EDGE_BODY(sn2, A2, F2) EDGE_BODY(sn3, A3, F3)
    e += 4;
  }
  for (; e < end; ++e) {
    const int sn = sorted_src[e];
    const float4 A = *reinterpret_cast<const float4*>(el + sn * 4);
    const u16x4 F = *reinterpret_cast<const u16x4*>(featb + (size_t)sn * C_HH + lofs);
    EDGE_BODY(sn, A, F)
  }

  float r0 = 0.f, r1 = 0.f, r2 = 0.f, r3 = 0.f;
  if (end > start) {
    const float inv = 1.f / s;
    r0 = a0 * inv; r1 = a1 * inv; r2 = a2 * inv; r3 = a3 * inv;
  }
  const float4 bb = *reinterpret_cast<const float4*>(bias + lane * 4);
  r0 = fmaxf(r0 + bb.x, 0.f);
  r1 = fmaxf(r1 + bb.y, 0.f);
  r2 = fmaxf(r2 + bb.z, 0.f);
  r3 = fmaxf(r3 + bb.w, 0.f);

  if (!HEAD) {
    u16x4 o;
    o[0] = f2bf(r0); o[1] = f2bf(r1); o[2] = f2bf(r2); o[3] = f2bf(r3);
    *reinterpret_cast<u16x4*>(out + (size_t)node * C_HH + lofs) = o;
  } else {
    const float4 q = *reinterpret_cast<const float4*>(qv + lane * 4);
    float v = fmaf(r0, q.x, fmaf(r1, q.y, fmaf(r2, q.z, r3 * q.w)));
#pragma unroll
    for (int off = 32; off; off >>= 1) v += __shfl_xor(v, off);
    if (lane == 0) outf[node] = 1.f / (1.f + __expf(-(v + cv[0])));
  }
}

extern "C" void kernel_launch(void* const* d_in, const int* in_sizes, int n_in,
                              void* d_out, int out_size, void* d_ws, size_t ws_size,
                              hipStream_t stream) {
  const float* x = (const float*)d_in[0];
  const int* src = (const int*)d_in[1];
  const int* dst = (const int*)d_in[2];
  const float* embed_W = (const float*)d_in[3];
  const float* embed_b = (const float*)d_in[4];
  const float* W1 = (const float*)d_in[5];
  const float* al1 = (const float*)d_in[6];
  const float* ar1 = (const float*)d_in[7];
  const float* b1 = (const float*)d_in[8];
  const float* W2 = (const float*)d_in[9];
  const float* al2 = (const float*)d_in[10];
  const float* ar2 = (const float*)d_in[11];
  const float* b2 = (const float*)d_in[12];
  const float* p1_W = (const float*)d_in[13];
  const float* p1_b = (const float*)d_in[14];
  const float* p2_W = (const float*)d_in[15];
  const float* p2_b = (const float*)d_in[16];

  char* ws = (char*)d_ws;
  ushort_t* featb = (ushort_t*)(ws + 0);          // N*256 bf16 = 25.6 MB
  ushort_t* houtb = (ushort_t*)(ws + 25600000);   // N*256 bf16 = 25.6 MB
  float* el = (float*)(ws + 51200000);            // N*4 f32
  float* er = (float*)(ws + 52000000);            // N*4 f32
  int* rowptr = (int*)(ws + 52800000);            // N+1
  int* cursor = (int*)(ws + 53100000);            // N
  int* partial = (int*)(ws + 53400000);           // 256
  int* sorted_src = (int*)(ws + 53500000);        // E = 2 MB
  ushort_t* WcT = (ushort_t*)(ws + 55600000);     // 256*256 bf16 = 128 KB
  ushort_t* w2T = (ushort_t*)(ws + 55800000);     // 256*256 bf16 = 128 KB
  float* bc = (float*)(ws + 56000000);            // 256 f32
  float* qv = (float*)(ws + 56010000);            // 256 f32
  float* cv = (float*)(ws + 56020000);            // 1 f32

  const int gEdge = (NE + 255) / 256;   // 1954
  const int nScanB = (NN + 255) / 256;  // 196
  const int gGemm = (NN + 31) / 32;     // 1563
  const int gNode = NN / 4;             // 12500

  // ---- CSR build (dst shared by both layers) ----
  hipMemsetAsync(rowptr, 0, (NN + 1) * sizeof(int), stream);
  hist_kernel<<<gEdge, 256, 0, stream>>>(dst, rowptr);
  scan1_kernel<<<nScanB, 256, 0, stream>>>(rowptr, partial);
  scan2_kernel<<<1, 256, 0, stream>>>(partial, nScanB);
  scan3_kernel<<<nScanB + 1, 256, 0, stream>>>(rowptr, partial, cursor);
  scatter_kernel<<<gEdge, 256, 0, stream>>>(src, dst, cursor, sorted_src);

  // ---- weight prep: Wc = eW@W1, bc = eb@W1, q = p1@p2, c ----
  prep_kernel<<<515, 256, 0, stream>>>(embed_W, W1, embed_b, W2, p1_W, p1_b, p2_W, p2_b,
                                       WcT, w2T, bc, qv, cv);

  // ---- GAT layer 1: featb = bf16(x @ Wc + bc), el/er fused (f32 A converted in-reg) ----
  gemm_fused<true, true><<<gGemm, 256, 0, stream>>>(x, WcT, bc, al1, ar1, el, er, featb, NN);
  aggr_fused_kernel<false><<<gNode, 256, 0, stream>>>(rowptr, sorted_src, el, er, featb, b1,
                                                      houtb, nullptr, nullptr, nullptr);

  // ---- GAT layer 2: featb = bf16(houtb @ W2), el/er fused; aggr fuses head+sigmoid ----
  gemm_fused<false, false><<<gGemm, 256, 0, stream>>>(houtb, w2T, nullptr, al2, ar2, el, er,
                                                      featb, NN);
  aggr_fused_kernel<true><<<gNode, 256, 0, stream>>>(rowptr, sorted_src, el, er, featb, b2,
                                                     nullptr, qv, cv, (float*)d_out);
}

// Round 12
// 356.808 us; speedup vs baseline: 1.0911x; 1.0911x over previous
//
#include <hip/hip_runtime.h>
#include <hip/hip_bf16.h>

// GAT: N=50000 nodes, E=500000 edges, IN=256, HID=64, H=4 heads (H*HID=256)
#define NN 50000
#define NE 500000
#define C_HH 256  // H*HID

typedef __attribute__((ext_vector_type(8))) short s16x8;
typedef __attribute__((ext_vector_type(4))) float f32x4;
typedef __attribute__((ext_vector_type(4))) unsigned short u16x4;
typedef unsigned short ushort_t;

__device__ __forceinline__ float lrelu(float x) { return x > 0.f ? x : 0.2f * x; }

__device__ __forceinline__ ushort_t f2bf(float f) {
  unsigned u = __float_as_uint(f);
  u = (u + 0x7FFFu + ((u >> 16) & 1u)) >> 16;
  return (ushort_t)u;
}
__device__ __forceinline__ float bf2f(ushort_t u) {
  return __uint_as_float(((unsigned)u) << 16);
}
__device__ __forceinline__ float sel_head(float4 v, int head) {
  const float x0 = (head & 1) ? v.y : v.x;
  const float x1 = (head & 1) ? v.w : v.z;
  return (head & 2) ? x1 : x0;
}

// ---------------- x -> bf16 bulk convert (grid-stride, 8 elems/thread) ----------------
__global__ __launch_bounds__(256) void xb_kernel(const float* __restrict__ in,
                                                 ushort_t* __restrict__ out) {
  const int n8 = NN * 256 / 8;
  for (int i = blockIdx.x * 256 + threadIdx.x; i < n8; i += gridDim.x * 256) {
    const f32x4 v0 = reinterpret_cast<const f32x4*>(in)[2 * i];
    const f32x4 v1 = reinterpret_cast<const f32x4*>(in)[2 * i + 1];
    s16x8 o;
    o[0] = (short)f2bf(v0[0]); o[1] = (short)f2bf(v0[1]);
    o[2] = (short)f2bf(v0[2]); o[3] = (short)f2bf(v0[3]);
    o[4] = (short)f2bf(v1[0]); o[5] = (short)f2bf(v1[1]);
    o[6] = (short)f2bf(v1[2]); o[7] = (short)f2bf(v1[3]);
    reinterpret_cast<s16x8*>(out)[i] = o;
  }
}

// ---------------- prep: fold embed into W1; fragment-order the B matrices ----------------
// Fragment layout: element for (gnt, ks, lane, j) at ((gnt*8+ks)*64 + lane)*8 + j,
// value = W[k][n] with k = ks*32 + (lane>>4)*8 + j, n = gnt*16 + (lane&15).
// -> a wave's B-load for (gnt,ks) is base + lane*16B: fully coalesced 1 KB.
__global__ __launch_bounds__(256) void prep_kernel(const float* __restrict__ eW,
                                                   const float* __restrict__ W1,
                                                   const float* __restrict__ eb,
                                                   const float* __restrict__ W2,
                                                   const float* __restrict__ p1W,
                                                   const float* __restrict__ p1b,
                                                   const float* __restrict__ p2W,
                                                   const float* __restrict__ p2b,
                                                   ushort_t* __restrict__ WcT,
                                                   ushort_t* __restrict__ w2T,
                                                   float* __restrict__ bc,
                                                   float* __restrict__ qv,
                                                   float* __restrict__ cv) {
  int idx = blockIdx.x * 256 + threadIdx.x;
  if (idx < 65536) {                       // WcT (fragment order): Wc = eW @ W1
    const int j = idx & 7;
    const int lane = (idx >> 3) & 63;
    const int ks = (idx >> 9) & 7;
    const int gnt = (idx >> 12) & 15;
    const int k = ks * 32 + (lane >> 4) * 8 + j;
    const int n = gnt * 16 + (lane & 15);
    float s = 0.f;
#pragma unroll 8
    for (int jj = 0; jj < 64; ++jj) s = fmaf(eW[k * 64 + jj], W1[jj * 256 + n], s);
    WcT[idx] = f2bf(s);
  } else if (idx < 131072) {               // w2T (fragment order)
    const int t = idx - 65536;
    const int j = t & 7;
    const int lane = (t >> 3) & 63;
    const int ks = (t >> 9) & 7;
    const int gnt = (t >> 12) & 15;
    const int k = ks * 32 + (lane >> 4) * 8 + j;
    const int n = gnt * 16 + (lane & 15);
    w2T[t] = f2bf(W2[k * 256 + n]);
  } else if (idx < 131328) {               // bc = eb @ W1
    const int n = idx - 131072;
    float s = 0.f;
#pragma unroll 8
    for (int j = 0; j < 64; ++j) s = fmaf(eb[j], W1[j * 256 + n], s);
    bc[n] = s;
  } else if (idx < 131584) {               // qv = p1_W @ p2_W
    const int k = idx - 131328;
    float s = 0.f;
#pragma unroll 8
    for (int j = 0; j < 64; ++j) s = fmaf(p1W[k * 64 + j], p2W[j], s);
    qv[k] = s;
  } else if (idx == 131584) {              // cv
    float s = p2b[0];
    for (int j = 0; j < 64; ++j) s = fmaf(p1b[j], p2W[j], s);
    cv[0] = s;
  }
}

// ---------------- MFMA GEMM [M,256]@[256,256] + fused el/er, high-occupancy form ----------------
// Block = 256 thr = 4 waves; wave w = head w (cols 64w..64w+64); block covers 16 rows.
// Grid = M/16 = 3125 (M divisible by 16 -> no bounds checks). Small per-wave state
// (a[8]=32 VGPR, acc=16) -> high occupancy; TLP hides latency (aggr-style).
// B is fragment-ordered (see prep): each B load = base + lane*16B, coalesced.
// C/D layout: col=lane&15, row=(lane>>4)*4+reg (HW-verified r4).
template <bool BIAS>
__global__ __launch_bounds__(256) void gemm_fused(const ushort_t* __restrict__ A,
                                                  const ushort_t* __restrict__ WT,
                                                  const float* __restrict__ bc,
                                                  const float* __restrict__ al,
                                                  const float* __restrict__ ar,
                                                  float* __restrict__ el,
                                                  float* __restrict__ er,
                                                  ushort_t* __restrict__ Cout) {
  const int wid = threadIdx.x >> 6;   // head / col-group
  const int lane = threadIdx.x & 63;
  const int row0 = blockIdx.x * 16;
  const int rA = lane & 15;
  const int kg = lane >> 4;
  const int c0 = wid * 64;

  // stage all 8 A fragments (shared across the 4 waves via L1)
  const ushort_t* Arow = A + (size_t)(row0 + rA) * 256 + kg * 8;
  s16x8 a[8];
#pragma unroll
  for (int ks = 0; ks < 8; ++ks) a[ks] = *reinterpret_cast<const s16x8*>(Arow + ks * 32);

  f32x4 acc[4] = {};
#pragma unroll
  for (int ks = 0; ks < 8; ++ks) {
#pragma unroll
    for (int nt = 0; nt < 4; ++nt) {
      const s16x8 b = *reinterpret_cast<const s16x8*>(
          WT + ((size_t)((wid * 4 + nt) * 8 + ks)) * 512 + lane * 8);
      acc[nt] = __builtin_amdgcn_mfma_f32_16x16x32_bf16(a[ks], b, acc[nt], 0, 0, 0);
    }
  }

  if (BIAS) {
#pragma unroll
    for (int nt = 0; nt < 4; ++nt) {
      const float bv = bc[c0 + nt * 16 + rA];
#pragma unroll
      for (int i = 0; i < 4; ++i) acc[nt][i] += bv;
    }
  }

  // store bf16 C
#pragma unroll
  for (int nt = 0; nt < 4; ++nt) {
    const int col = c0 + nt * 16 + rA;
#pragma unroll
    for (int i = 0; i < 4; ++i) {
      const int row = row0 + kg * 4 + i;
      Cout[(size_t)row * 256 + col] = f2bf(acc[nt][i]);
    }
  }

  // fused el/er for head `wid`
  float alv[4], arv[4];
#pragma unroll
  for (int nt = 0; nt < 4; ++nt) {
    alv[nt] = al[c0 + nt * 16 + rA];
    arv[nt] = ar[c0 + nt * 16 + rA];
  }
#pragma unroll
  for (int i = 0; i < 4; ++i) {
    float e = 0.f, r = 0.f;
#pragma unroll
    for (int nt = 0; nt < 4; ++nt) {
      e = fmaf(acc[nt][i], alv[nt], e);
      r = fmaf(acc[nt][i], arv[nt], r);
    }
#pragma unroll
    for (int m = 1; m < 16; m <<= 1) {
      e += __shfl_xor(e, m);
      r += __shfl_xor(r, m);
    }
    const int row = row0 + kg * 4 + i;
    if (rA == 0) {
      el[row * 4 + wid] = e;
      er[row * 4 + wid] = r;
    }
  }
}

// ---------------- CSR build: histogram -> scan -> scatter ----------------
__global__ __launch_bounds__(256) void hist_kernel(const int* __restrict__ dst,
                                                   int* __restrict__ rowptr) {
  const int e = blockIdx.x * 256 + threadIdx.x;
  if (e < NE) atomicAdd(&rowptr[dst[e]], 1);
}

__global__ __launch_bounds__(256) void scan1_kernel(int* __restrict__ rowptr,
                                                    int* __restrict__ partial) {
  __shared__ int sh[256];
  const int t = threadIdx.x;
  const int i = blockIdx.x * 256 + t;
  const int v = (i < NN) ? rowptr[i] : 0;
  sh[t] = v;
  __syncthreads();
#pragma unroll
  for (int off = 1; off < 256; off <<= 1) {
    int x = (t >= off) ? sh[t - off] : 0;
    __syncthreads();
    sh[t] += x;
    __syncthreads();
  }
  if (i < NN) rowptr[i] = sh[t] - v;
  if (t == 255) partial[blockIdx.x] = sh[255];
}

__global__ __launch_bounds__(256) void scan2_kernel(int* __restrict__ partial, int npb) {
  __shared__ int sh[256];
  const int t = threadIdx.x;
  const int v = (t < npb) ? partial[t] : 0;
  sh[t] = v;
  __syncthreads();
#pragma unroll
  for (int off = 1; off < 256; off <<= 1) {
    int x = (t >= off) ? sh[t - off] : 0;
    __syncthreads();
    sh[t] += x;
    __syncthreads();
  }
  if (t < npb) partial[t] = sh[t] - v;
}

__global__ __launch_bounds__(256) void scan3_kernel(int* __restrict__ rowptr,
                                                    const int* __restrict__ partial,
                                                    int* __restrict__ cursor) {
  const int i = blockIdx.x * 256 + threadIdx.x;
  if (i < NN) {
    const int r = rowptr[i] + partial[i >> 8];
    rowptr[i] = r;
    cursor[i] = r;
  } else if (i == NN) {
    rowptr[NN] = NE;
  }
}

__global__ __launch_bounds__(256) void scatter_kernel(const int* __restrict__ src,
                                                      const int* __restrict__ dst,
                                                      int* __restrict__ cursor,
                                                      int* __restrict__ sorted_src) {
  const int e = blockIdx.x * 256 + threadIdx.x;
  if (e >= NE) return;
  const int pos = atomicAdd(&cursor[dst[e]], 1);
  sorted_src[pos] = src[e];
}

// ---------------- fused per-dst softmax-aggregation + bias + relu (bf16 feat) ----------------
// one 64-lane wave per dst node; lane owns cols 4l..4l+3 (all in head l>>4).
// 8-edge software pipeline (16 outstanding loads), 4-chunk + scalar tail.
// HEAD=true: don't store hout; fuse out[n] = sigmoid(relu_row · qv + cv) instead.
#define EDGE_BODY(SN, AV, FV)                                    \
  {                                                              \
    const float w_ = __expf(lrelu(sel_head(AV, head) + erh));    \
    a0 = fmaf(w_, bf2f(FV[0]), a0);                              \
    a1 = fmaf(w_, bf2f(FV[1]), a1);                              \
    a2 = fmaf(w_, bf2f(FV[2]), a2);                              \
    a3 = fmaf(w_, bf2f(FV[3]), a3);                              \
    s += w_;                                                     \
  }

template <bool HEAD>
__global__ __launch_bounds__(256) void aggr_fused_kernel(const int* __restrict__ rowptr,
                                                         const int* __restrict__ sorted_src,
                                                         const float* __restrict__ el,
                                                         const float* __restrict__ er,
                                                         const ushort_t* __restrict__ featb,
                                                         const float* __restrict__ bias,
                                                         ushort_t* __restrict__ out,
                                                         const float* __restrict__ qv,
                                                         const float* __restrict__ cv,
                                                         float* __restrict__ outf) {
  const int node = blockIdx.x * 4 + (threadIdx.x >> 6);
  const int lane = threadIdx.x & 63;
  const int head = lane >> 4;
  const int start = rowptr[node];
  const int end = rowptr[node + 1];
  const float erh = sel_head(*reinterpret_cast<const float4*>(er + node * 4), head);
  const size_t lofs = (size_t)lane * 4;

  float a0 = 0.f, a1 = 0.f, a2 = 0.f, a3 = 0.f, s = 0.f;
  int e = start;
  for (; e + 8 <= end; e += 8) {
    const int sn0 = sorted_src[e + 0];
    const int sn1 = sorted_src[e + 1];
    const int sn2 = sorted_src[e + 2];
    const int sn3 = sorted_src[e + 3];
    const int sn4 = sorted_src[e + 4];
    const int sn5 = sorted_src[e + 5];
    const int sn6 = sorted_src[e + 6];
    const int sn7 = sorted_src[e + 7];
    const float4 A0 = *reinterpret_cast<const float4*>(el + sn0 * 4);
    const float4 A1 = *reinterpret_cast<const float4*>(el + sn1 * 4);
    const float4 A2 = *reinterpret_cast<const float4*>(el + sn2 * 4);
    const float4 A3 = *reinterpret_cast<const float4*>(el + sn3 * 4);
    const float4 A4 = *reinterpret_cast<const float4*>(el + sn4 * 4);
    const float4 A5 = *reinterpret_cast<const float4*>(el + sn5 * 4);
    const float4 A6 = *reinterpret_cast<const float4*>(el + sn6 * 4);
    const float4 A7 = *reinterpret_cast<const float4*>(el + sn7 * 4);
    const u16x4 F0 = *reinterpret_cast<const u16x4*>(featb + (size_t)sn0 * C_HH + lofs);
    const u16x4 F1 = *reinterpret_cast<const u16x4*>(featb + (size_t)sn1 * C_HH + lofs);
    const u16x4 F2 = *reinterpret_cast<const u16x4*>(featb + (size_t)sn2 * C_HH + lofs);
    const u16x4 F3 = *reinterpret_cast<const u16x4*>(featb + (size_t)sn3 * C_HH + lofs);
    const u16x4 F4 = *reinterpret_cast<const u16x4*>(featb + (size_t)sn4 * C_HH + lofs);
    const u16x4 F5 = *reinterpret_cast<const u16x4*>(featb + (size_t)sn5 * C_HH + lofs);
    const u16x4 F6 = *reinterpret_cast<const u16x4*>(featb + (size_t)sn6 * C_HH + lofs);
    const u16x4 F7 = *reinterpret_cast<const u16x4*>(featb + (size_t)sn7 * C_HH + lofs);
    EDGE_BODY(sn0, A0, F0) EDGE_BODY(sn1, A1, F1)
    EDGE_BODY(sn2, A2, F2) EDGE_BODY(sn3, A3, F3)
    EDGE_BODY(sn4, A4, F4) EDGE_BODY(sn5, A5, F5)
    EDGE_BODY(sn6, A6, F6) EDGE_BODY(sn7, A7, F7)
  }
  if (e + 4 <= end) {
    const int sn0 = sorted_src[e + 0];
    const int sn1 = sorted_src[e + 1];
    const int sn2 = sorted_src[e + 2];
    const int sn3 = sorted_src[e + 3];
    const float4 A0 = *reinterpret_cast<const float4*>(el + sn0 * 4);
    const float4 A1 = *reinterpret_cast<const float4*>(el + sn1 * 4);
    const float4 A2 = *reinterpret_cast<const float4*>(el + sn2 * 4);
    const float4 A3 = *reinterpret_cast<const float4*>(el + sn3 * 4);
    const u16x4 F0 = *reinterpret_cast<const u16x4*>(featb + (size_t)sn0 * C_HH + lofs);
    const u16x4 F1 = *reinterpret_cast<const u16x4*>(featb + (size_t)sn1 * C_HH + lofs);
    const u16x4 F2 = *reinterpret_cast<const u16x4*>(featb + (size_t)sn2 * C_HH + lofs);
    const u16x4 F3 = *reinterpret_cast<const u16x4*>(featb + (size_t)sn3 * C_HH + lofs);
    EDGE_BODY(sn0, A0, F0) EDGE_BODY(sn1, A1, F1)
    EDGE_BODY(sn2, A2, F2) EDGE_BODY(sn3, A3, F3)
    e += 4;
  }
  for (; e < end; ++e) {
    const int sn = sorted_src[e];
    const float4 A = *reinterpret_cast<const float4*>(el + sn * 4);
    const u16x4 F = *reinterpret_cast<const u16x4*>(featb + (size_t)sn * C_HH + lofs);
    EDGE_BODY(sn, A, F)
  }

  float r0 = 0.f, r1 = 0.f, r2 = 0.f, r3 = 0.f;
  if (end > start) {
    const float inv = 1.f / s;
    r0 = a0 * inv; r1 = a1 * inv; r2 = a2 * inv; r3 = a3 * inv;
  }
  const float4 bb = *reinterpret_cast<const float4*>(bias + lane * 4);
  r0 = fmaxf(r0 + bb.x, 0.f);
  r1 = fmaxf(r1 + bb.y, 0.f);
  r2 = fmaxf(r2 + bb.z, 0.f);
  r3 = fmaxf(r3 + bb.w, 0.f);

  if (!HEAD) {
    u16x4 o;
    o[0] = f2bf(r0); o[1] = f2bf(r1); o[2] = f2bf(r2); o[3] = f2bf(r3);
    *reinterpret_cast<u16x4*>(out + (size_t)node * C_HH + lofs) = o;
  } else {
    const float4 q = *reinterpret_cast<const float4*>(qv + lane * 4);
    float v = fmaf(r0, q.x, fmaf(r1, q.y, fmaf(r2, q.z, r3 * q.w)));
#pragma unroll
    for (int off = 32; off; off >>= 1) v += __shfl_xor(v, off);
    if (lane == 0) outf[node] = 1.f / (1.f + __expf(-(v + cv[0])));
  }
}

extern "C" void kernel_launch(void* const* d_in, const int* in_sizes, int n_in,
                              void* d_out, int out_size, void* d_ws, size_t ws_size,
                              hipStream_t stream) {
  const float* x = (const float*)d_in[0];
  const int* src = (const int*)d_in[1];
  const int* dst = (const int*)d_in[2];
  const float* embed_W = (const float*)d_in[3];
  const float* embed_b = (const float*)d_in[4];
  const float* W1 = (const float*)d_in[5];
  const float* al1 = (const float*)d_in[6];
  const float* ar1 = (const float*)d_in[7];
  const float* b1 = (const float*)d_in[8];
  const float* W2 = (const float*)d_in[9];
  const float* al2 = (const float*)d_in[10];
  const float* ar2 = (const float*)d_in[11];
  const float* b2 = (const float*)d_in[12];
  const float* p1_W = (const float*)d_in[13];
  const float* p1_b = (const float*)d_in[14];
  const float* p2_W = (const float*)d_in[15];
  const float* p2_b = (const float*)d_in[16];

  char* ws = (char*)d_ws;
  ushort_t* featb = (ushort_t*)(ws + 0);          // N*256 bf16 = 25.6 MB
  ushort_t* houtb = (ushort_t*)(ws + 25600000);   // N*256 bf16 = 25.6 MB
  ushort_t* xb = (ushort_t*)(ws + 51200000);      // N*256 bf16 = 25.6 MB
  float* el = (float*)(ws + 76800000);            // N*4 f32
  float* er = (float*)(ws + 77600000);            // N*4 f32
  int* rowptr = (int*)(ws + 78400000);            // N+1
  int* cursor = (int*)(ws + 78700000);            // N
  int* partial = (int*)(ws + 79000000);           // 256
  int* sorted_src = (int*)(ws + 79100000);        // E = 2 MB
  ushort_t* WcT = (ushort_t*)(ws + 81200000);     // 256*256 bf16 = 128 KB (fragment order)
  ushort_t* w2T = (ushort_t*)(ws + 81400000);     // 256*256 bf16 = 128 KB (fragment order)
  float* bc = (float*)(ws + 81600000);            // 256 f32
  float* qv = (float*)(ws + 81610000);            // 256 f32
  float* cv = (float*)(ws + 81620000);            // 1 f32

  const int gEdge = (NE + 255) / 256;   // 1954
  const int nScanB = (NN + 255) / 256;  // 196
  const int gGemm = NN / 16;            // 3125
  const int gNode = NN / 4;             // 12500

  // ---- CSR build (dst shared by both layers) ----
  hipMemsetAsync(rowptr, 0, (NN + 1) * sizeof(int), stream);
  hist_kernel<<<gEdge, 256, 0, stream>>>(dst, rowptr);
  scan1_kernel<<<nScanB, 256, 0, stream>>>(rowptr, partial);
  scan2_kernel<<<1, 256, 0, stream>>>(partial, nScanB);
  scan3_kernel<<<nScanB + 1, 256, 0, stream>>>(rowptr, partial, cursor);
  scatter_kernel<<<gEdge, 256, 0, stream>>>(src, dst, cursor, sorted_src);

  // ---- weight prep + x conversion ----
  prep_kernel<<<515, 256, 0, stream>>>(embed_W, W1, embed_b, W2, p1_W, p1_b, p2_W, p2_b,
                                       WcT, w2T, bc, qv, cv);
  xb_kernel<<<2048, 256, 0, stream>>>(x, xb);

  // ---- GAT layer 1: featb = bf16(xb @ Wc + bc), el/er fused ----
  gemm_fused<true><<<gGemm, 256, 0, stream>>>(xb, WcT, bc, al1, ar1, el, er, featb);
  aggr_fused_kernel<false><<<gNode, 256, 0, stream>>>(rowptr, sorted_src, el, er, featb, b1,
                                                      houtb, nullptr, nullptr, nullptr);

  // ---- GAT layer 2: featb = bf16(houtb @ W2), el/er fused; aggr fuses head+sigmoid ----
  gemm_fused<false><<<gGemm, 256, 0, stream>>>(houtb, w2T, nullptr, al2, ar2, el, er, featb);
  aggr_fused_kernel<true><<<gNode, 256, 0, stream>>>(rowptr, sorted_src, el, er, featb, b2,
                                                     nullptr, qv, cv, (float*)d_out);
}